// Round 3
// baseline (353.275 us; speedup 1.0000x reference)
//
#include <hip/hip_runtime.h>
#include <hip/hip_bf16.h>

#define NROWS 131072
#define KEXP 16
#define MPC 128
#define DIMD 64

typedef float f32x4  __attribute__((ext_vector_type(4)));
typedef float f32x16 __attribute__((ext_vector_type(16)));
typedef short s16x8  __attribute__((ext_vector_type(8)));

#define L2E 1.4426950408889634f
#define LN2 0.6931471805599453f

static __device__ inline unsigned int b2u(__hip_bfloat162 h) {
    union { __hip_bfloat162 h; unsigned int u; } c;
    c.h = h;
    return c.u;
}

static __device__ inline int4 cvt8s(float4 f0, float4 f1, float sc) {
    __hip_bfloat162 p0 = __float22bfloat162_rn(make_float2(f0.x * sc, f0.y * sc));
    __hip_bfloat162 p1 = __float22bfloat162_rn(make_float2(f0.z * sc, f0.w * sc));
    __hip_bfloat162 p2 = __float22bfloat162_rn(make_float2(f1.x * sc, f1.y * sc));
    __hip_bfloat162 p3 = __float22bfloat162_rn(make_float2(f1.z * sc, f1.w * sc));
    int4 pk;
    pk.x = (int)b2u(p0); pk.y = (int)b2u(p1); pk.z = (int)b2u(p2); pk.w = (int)b2u(p3);
    return pk;
}

// async 16B/lane global->LDS DMA (wave-uniform LDS base + lane*16)
static __device__ inline void async_copy16(const void* g, void* l) {
    __builtin_amdgcn_global_load_lds(
        (const __attribute__((address_space(1))) unsigned int*)g,
        (__attribute__((address_space(3))) unsigned int*)l, 16, 0, 0);
}

// abff: per expert 20 chunks [mt(4)][c(5)] of 64 int4 (1 KB each) = 20 KB.
//   c<4 : A-frag, value j = a[k][mt*32 + (ul&31)][c*16 + (ul>>5)*8 + j] * L2E
//   c==4: bias chunk — A[m][k'=0] = b[k][mt*32+m] * L2E (ul<32, element 0), else 0
// Also zeroes out[] (replaces the hipMemsetAsync launch).
__global__ void prep_kernel(const float* __restrict__ a, const float* __restrict__ b,
                            short* __restrict__ abff, float* __restrict__ out) {
    const int u   = blockIdx.x * 256 + threadIdx.x;   // 0..20479
    const int k   = u / 1280;
    const int rem = u - k * 1280;
    const int mt  = rem / 320;
    const int rc  = rem - mt * 320;
    const int c   = rc >> 6;
    const int ul  = rc & 63;
    int4 pk;
    if (c < 4) {
        const float* p = a + (size_t)(k * MPC + mt * 32 + (ul & 31)) * DIMD
                           + c * 16 + (ul >> 5) * 8;
        pk = cvt8s(*(const float4*)(p), *(const float4*)(p + 4), L2E);
    } else {
        pk.x = 0; pk.y = 0; pk.z = 0; pk.w = 0;
        if (ul < 32) {
            union { __hip_bfloat16 h; unsigned short us; } cv;
            cv.h = __float2bfloat16(b[k * MPC + mt * 32 + ul] * L2E);
            pk.x = (int)cv.us;   // element 0 = bias, elements 1..7 = 0
        }
    }
    *(int4*)(abff + (size_t)u * 8) = pk;

    // zero the output (20480 threads grid-stride over 131072 floats)
    for (int i = u; i < NROWS; i += 80 * 256) out[i] = 0.f;
}

// Block = 256 threads (4 waves); wave owns 64 rows (2 n-tiles) of x PERSISTENT
// in registers (Bf[2][4], 32 VGPR). family = blockIdx&3 -> experts family*4..+3;
// grid = 2048. LDS = 2 x 10 KB (half-expert / 2-mtile double buffer) -> 20 KB/block
// -> 8 blocks/CU -> 32 waves/CU (2x round-0 occupancy; __launch_bounds__(256,8)
// pins VGPR <= 64; round-0 measured 52 with the same inner structure).
// Per half-expert stage: 10 chunk DMAs (global_load_lds dwordx4) issued for
// stage g+1 while computing stage g. MFMA 32x32x16 transposed (m on C-rows);
// bias as 5th MFMA with constant B. Softmax m-sum in-lane (hw v_exp_f32) +
// ONE shfl_xor(32)/expert.
__global__ __launch_bounds__(256, 8)
void fused_kernel(const float* __restrict__ x, const float* __restrict__ s,
                  const short* __restrict__ abff, float* __restrict__ out) {
    __shared__ int4 abuf[2][640];   // 2 x 10 KB

    const int tid  = threadIdx.x;
    const int w    = tid >> 6;
    const int l    = tid & 63;
    const int ln   = l & 31;
    const int half = l >> 5;

    const int family = blockIdx.x & 3;
    const int r0w    = (blockIdx.x >> 2) * 256 + w * 64;

    // persistent x B-fragments: Bf[nt][c] = x[r0w + nt*32 + ln][c*16 + half*8 ..+7]
    union { int4 i; s16x8 v; } Bf[2][4];
#pragma unroll
    for (int nt = 0; nt < 2; ++nt)
#pragma unroll
        for (int c = 0; c < 4; ++c) {
            const float* gp = x + (size_t)(r0w + nt * 32 + ln) * DIMD + c * 16 + half * 8;
            float4 f0 = *(const float4*)(gp);
            float4 f1 = *(const float4*)(gp + 4);
            Bf[nt][c].i = cvt8s(f0, f1, 1.0f);
        }

    // constant bias-B: B[n][k'=0] = 1.0 (k'=0 lives on half==0 lanes, element 0)
    union { int4 i; s16x8 v; } Bones;
    Bones.i.x = (half == 0) ? 0x3F80 : 0;   // bf16(1.0) in element 0
    Bones.i.y = 0; Bones.i.z = 0; Bones.i.w = 0;

    const int kf0 = family * 4;

    // DMA stage 0 (expert kf0, mtiles 0-1): chunks 0..9, wave w takes ch = w+4i
    {
        const short* src = abff + (size_t)kf0 * 10240;
#pragma unroll
        for (int i = 0; i < 3; ++i) {
            const int ch = w + 4 * i;
            if (ch < 10)
                async_copy16(src + ch * 512 + l * 8, (char*)&abuf[0][0] + ch * 1024);
        }
    }
    __syncthreads();   // barrier drains DMA (vmcnt0 before s_barrier)

    float racc0 = 0.f, racc1 = 0.f;

#pragma unroll
    for (int k = 0; k < 4; ++k) {
        const int kf  = kf0 + k;
        const float sk2 = s[kf] * LN2;
        float esum0 = 0.f, esum1 = 0.f;

#pragma unroll
        for (int h = 0; h < 2; ++h) {
            const int g   = k * 2 + h;     // global stage 0..7
            const int buf = g & 1;

            // next stage's DMA into the other buffer (in flight during compute)
            if (g < 7) {
                const int gn = g + 1;
                const short* src = abff + (size_t)(kf0 + (gn >> 1)) * 10240
                                        + (size_t)(gn & 1) * 5120;
#pragma unroll
                for (int i = 0; i < 3; ++i) {
                    const int ch = w + 4 * i;
                    if (ch < 10)
                        async_copy16(src + ch * 512 + l * 8,
                                     (char*)&abuf[buf ^ 1][0] + ch * 1024);
                }
            }

#pragma unroll
            for (int mtl = 0; mtl < 2; ++mtl) {
                // A-frags incl. bias chunk (conflict-free b128: lane l -> l*16B)
                s16x8 Af[5];
#pragma unroll
                for (int c = 0; c < 5; ++c)
                    Af[c] = *(const s16x8*)((const short*)&abuf[buf][0]
                                            + (mtl * 5 + c) * 512 + l * 8);

                // ---- n-tile 0 chain ----
                {
                    f32x16 acc = {};
#pragma unroll
                    for (int c = 0; c < 4; ++c)
                        acc = __builtin_amdgcn_mfma_f32_32x32x16_bf16(Af[c], Bf[0][c].v, acc, 0, 0, 0);
                    acc = __builtin_amdgcn_mfma_f32_32x32x16_bf16(Af[4], Bones.v, acc, 0, 0, 0);
                    float s0 = 0.f, s1 = 0.f, s2 = 0.f, s3 = 0.f;
#pragma unroll
                    for (int r = 0; r < 4; ++r) {
                        s0 += __builtin_amdgcn_exp2f(acc[4 * r + 0]);
                        s1 += __builtin_amdgcn_exp2f(acc[4 * r + 1]);
                        s2 += __builtin_amdgcn_exp2f(acc[4 * r + 2]);
                        s3 += __builtin_amdgcn_exp2f(acc[4 * r + 3]);
                    }
                    esum0 += (s0 + s1) + (s2 + s3);
                }
                // ---- n-tile 1 chain ----
                {
                    f32x16 acc = {};
#pragma unroll
                    for (int c = 0; c < 4; ++c)
                        acc = __builtin_amdgcn_mfma_f32_32x32x16_bf16(Af[c], Bf[1][c].v, acc, 0, 0, 0);
                    acc = __builtin_amdgcn_mfma_f32_32x32x16_bf16(Af[4], Bones.v, acc, 0, 0, 0);
                    float s0 = 0.f, s1 = 0.f, s2 = 0.f, s3 = 0.f;
#pragma unroll
                    for (int r = 0; r < 4; ++r) {
                        s0 += __builtin_amdgcn_exp2f(acc[4 * r + 0]);
                        s1 += __builtin_amdgcn_exp2f(acc[4 * r + 1]);
                        s2 += __builtin_amdgcn_exp2f(acc[4 * r + 2]);
                        s3 += __builtin_amdgcn_exp2f(acc[4 * r + 3]);
                    }
                    esum1 += (s0 + s1) + (s2 + s3);
                }
            }

            __syncthreads();   // abuf[buf] free for next DMA; next buffer drained
        }

        // combine m-halves (lanes l and l^32), accumulate weighted lse
        float tot0 = esum0 + __shfl_xor(esum0, 32);
        float tot1 = esum1 + __shfl_xor(esum1, 32);
        racc0 = fmaf(sk2, __log2f(tot0), racc0);
        racc1 = fmaf(sk2, __log2f(tot1), racc1);
    }

    // half 0 lanes own n-tile 0 rows, half 1 lanes own n-tile 1 rows
    atomicAdd(&out[r0w + half * 32 + ln], half ? racc1 : racc0);
}

extern "C" void kernel_launch(void* const* d_in, const int* in_sizes, int n_in,
                              void* d_out, int out_size, void* d_ws, size_t ws_size,
                              hipStream_t stream) {
    const float* x = (const float*)d_in[0];
    const float* s = (const float*)d_in[1];
    const float* a = (const float*)d_in[2];
    const float* b = (const float*)d_in[3];
    float* out = (float*)d_out;

    short* abff = (short*)d_ws;   // 16 experts x 20 KB = 320 KB

    prep_kernel<<<80, 256, 0, stream>>>(a, b, abff, out);
    fused_kernel<<<NROWS / 64, 256, 0, stream>>>(x, s, abff, out);
}

// Round 4
// 123.416 us; speedup vs baseline: 2.8625x; 2.8625x over previous
//
#include <hip/hip_runtime.h>
#include <hip/hip_bf16.h>

#define NROWS 131072
#define KEXP 16
#define MPC 128
#define DIMD 64

typedef float f32x4  __attribute__((ext_vector_type(4)));
typedef float f32x16 __attribute__((ext_vector_type(16)));
typedef short s16x8  __attribute__((ext_vector_type(8)));

#define L2E 1.4426950408889634f
#define LN2 0.6931471805599453f

static __device__ inline unsigned int b2u(__hip_bfloat162 h) {
    union { __hip_bfloat162 h; unsigned int u; } c;
    c.h = h;
    return c.u;
}

static __device__ inline int4 cvt8s(float4 f0, float4 f1, float sc) {
    __hip_bfloat162 p0 = __float22bfloat162_rn(make_float2(f0.x * sc, f0.y * sc));
    __hip_bfloat162 p1 = __float22bfloat162_rn(make_float2(f0.z * sc, f0.w * sc));
    __hip_bfloat162 p2 = __float22bfloat162_rn(make_float2(f1.x * sc, f1.y * sc));
    __hip_bfloat162 p3 = __float22bfloat162_rn(make_float2(f1.z * sc, f1.w * sc));
    int4 pk;
    pk.x = (int)b2u(p0); pk.y = (int)b2u(p1); pk.z = (int)b2u(p2); pk.w = (int)b2u(p3);
    return pk;
}

// async 16B/lane global->LDS DMA (wave-uniform LDS base + lane*16)
static __device__ inline void async_copy16(const void* g, void* l) {
    __builtin_amdgcn_global_load_lds(
        (const __attribute__((address_space(1))) unsigned int*)g,
        (__attribute__((address_space(3))) unsigned int*)l, 16, 0, 0);
}

// abff: per expert 20 chunks [mt(4)][c(5)] of 64 int4 (1 KB each) = 20 KB.
//   c<4 : A-frag, value j = a[k][mt*32 + (ul&31)][c*16 + (ul>>5)*8 + j] * L2E
//   c==4: bias chunk — A[m][k'=0] = b[k][mt*32+m] * L2E (ul<32, element 0), else 0
// Also zeroes out[] (replaces the hipMemsetAsync launch).
__global__ void prep_kernel(const float* __restrict__ a, const float* __restrict__ b,
                            short* __restrict__ abff, float* __restrict__ out) {
    const int u   = blockIdx.x * 256 + threadIdx.x;   // 0..20479
    const int k   = u / 1280;
    const int rem = u - k * 1280;
    const int mt  = rem / 320;
    const int rc  = rem - mt * 320;
    const int c   = rc >> 6;
    const int ul  = rc & 63;
    int4 pk;
    if (c < 4) {
        const float* p = a + (size_t)(k * MPC + mt * 32 + (ul & 31)) * DIMD
                           + c * 16 + (ul >> 5) * 8;
        pk = cvt8s(*(const float4*)(p), *(const float4*)(p + 4), L2E);
    } else {
        pk.x = 0; pk.y = 0; pk.z = 0; pk.w = 0;
        if (ul < 32) {
            union { __hip_bfloat16 h; unsigned short us; } cv;
            cv.h = __float2bfloat16(b[k * MPC + mt * 32 + ul] * L2E);
            pk.x = (int)cv.us;   // element 0 = bias, elements 1..7 = 0
        }
    }
    *(int4*)(abff + (size_t)u * 8) = pk;

    // zero the output (20480 threads grid-stride over 131072 floats)
    for (int i = u; i < NROWS; i += 80 * 256) out[i] = 0.f;
}

// Block = 256 threads (4 waves); each wave owns 32 rows (ONE n-tile) of x
// persistent in registers (Bf[4], 16 VGPR). family = blockIdx&1 -> experts
// family*8..+7 (x HBM fetch stays 1x + L3-absorbed re-read). Block covers 128
// rows -> grid = 2048 -> 8 blocks/CU by LDS (2 x 10 KB half-expert double
// buffer = 20 KB; 8 x 20 KB = 160 KB/CU exactly). NO min-waves launch-bounds
// forcing and NO k-loop unroll pragma: round-3's spill disaster (WRITE_SIZE
// 476 MB of scratch) came from capping VGPR at 64 under a fully-unrolled loop.
// Two statically-indexed half-stages per expert: read abuf[0] / prefetch
// abuf[1], then read abuf[1] / prefetch next expert's abuf[0].
// MFMA 32x32x16 transposed (m on C-rows); bias as 5th MFMA with constant B.
// Softmax m-sum in-lane (hw v_exp_f32) + ONE shfl_xor(32)/expert.
__global__ __launch_bounds__(256, 4)
void fused_kernel(const float* __restrict__ x, const float* __restrict__ s,
                  const short* __restrict__ abff, float* __restrict__ out) {
    __shared__ int4 abuf[2][640];   // 2 x 10 KB

    const int tid  = threadIdx.x;
    const int w    = tid >> 6;
    const int l    = tid & 63;
    const int ln   = l & 31;
    const int half = l >> 5;

    const int family = blockIdx.x & 1;
    const int r0w    = (blockIdx.x >> 1) * 128 + w * 32;

    // persistent x B-fragment: Bf[c] = x[r0w + ln][c*16 + half*8 ..+7]
    union { int4 i; s16x8 v; } Bf[4];
#pragma unroll
    for (int c = 0; c < 4; ++c) {
        const float* gp = x + (size_t)(r0w + ln) * DIMD + c * 16 + half * 8;
        float4 f0 = *(const float4*)(gp);
        float4 f1 = *(const float4*)(gp + 4);
        Bf[c].i = cvt8s(f0, f1, 1.0f);
    }

    // constant bias-B: B[n][k'=0] = 1.0 (k'=0 lives on half==0 lanes, element 0)
    union { int4 i; s16x8 v; } Bones;
    Bones.i.x = (half == 0) ? 0x3F80 : 0;   // bf16(1.0) in element 0
    Bones.i.y = 0; Bones.i.z = 0; Bones.i.w = 0;

    const int kf0 = family * 8;

    // DMA initial stage (expert kf0, mtiles 0-1) into abuf[0]:
    // 10 chunks, wave w takes ch = w + 4*i
    {
        const short* src = abff + (size_t)kf0 * 10240;
#pragma unroll
        for (int i = 0; i < 3; ++i) {
            const int ch = w + 4 * i;
            if (ch < 10)
                async_copy16(src + ch * 512 + l * 8, (char*)&abuf[0][0] + ch * 1024);
        }
    }
    __syncthreads();   // barrier drains DMA (vmcnt0 before s_barrier)

    float racc = 0.f;

    for (int k = 0; k < 8; ++k) {   // runtime loop: keep code + registers small
        const int kf  = kf0 + k;
        const float sk2 = s[kf] * LN2;
        float esum = 0.f;

        // ---------- half-stage 0: compute abuf[0], prefetch half 1 -> abuf[1]
        {
            const short* src = abff + (size_t)kf * 10240 + 5120;
#pragma unroll
            for (int i = 0; i < 3; ++i) {
                const int ch = w + 4 * i;
                if (ch < 10)
                    async_copy16(src + ch * 512 + l * 8, (char*)&abuf[1][0] + ch * 1024);
            }
        }
#pragma unroll
        for (int mtl = 0; mtl < 2; ++mtl) {
            s16x8 Af[5];
#pragma unroll
            for (int c = 0; c < 5; ++c)
                Af[c] = *(const s16x8*)((const short*)&abuf[0][0]
                                        + (mtl * 5 + c) * 512 + l * 8);
            f32x16 acc = {};
#pragma unroll
            for (int c = 0; c < 4; ++c)
                acc = __builtin_amdgcn_mfma_f32_32x32x16_bf16(Af[c], Bf[c].v, acc, 0, 0, 0);
            acc = __builtin_amdgcn_mfma_f32_32x32x16_bf16(Af[4], Bones.v, acc, 0, 0, 0);
            float s0 = 0.f, s1 = 0.f, s2 = 0.f, s3 = 0.f;
#pragma unroll
            for (int r = 0; r < 4; ++r) {
                s0 += __builtin_amdgcn_exp2f(acc[4 * r + 0]);
                s1 += __builtin_amdgcn_exp2f(acc[4 * r + 1]);
                s2 += __builtin_amdgcn_exp2f(acc[4 * r + 2]);
                s3 += __builtin_amdgcn_exp2f(acc[4 * r + 3]);
            }
            esum += (s0 + s1) + (s2 + s3);
        }
        __syncthreads();   // abuf[0] free; abuf[1] drained

        // ---------- half-stage 1: compute abuf[1], prefetch next expert -> abuf[0]
        if (k < 7) {
            const short* src = abff + (size_t)(kf + 1) * 10240;
#pragma unroll
            for (int i = 0; i < 3; ++i) {
                const int ch = w + 4 * i;
                if (ch < 10)
                    async_copy16(src + ch * 512 + l * 8, (char*)&abuf[0][0] + ch * 1024);
            }
        }
#pragma unroll
        for (int mtl = 0; mtl < 2; ++mtl) {
            s16x8 Af[5];
#pragma unroll
            for (int c = 0; c < 5; ++c)
                Af[c] = *(const s16x8*)((const short*)&abuf[1][0]
                                        + (mtl * 5 + c) * 512 + l * 8);
            f32x16 acc = {};
#pragma unroll
            for (int c = 0; c < 4; ++c)
                acc = __builtin_amdgcn_mfma_f32_32x32x16_bf16(Af[c], Bf[c].v, acc, 0, 0, 0);
            acc = __builtin_amdgcn_mfma_f32_32x32x16_bf16(Af[4], Bones.v, acc, 0, 0, 0);
            float s0 = 0.f, s1 = 0.f, s2 = 0.f, s3 = 0.f;
#pragma unroll
            for (int r = 0; r < 4; ++r) {
                s0 += __builtin_amdgcn_exp2f(acc[4 * r + 0]);
                s1 += __builtin_amdgcn_exp2f(acc[4 * r + 1]);
                s2 += __builtin_amdgcn_exp2f(acc[4 * r + 2]);
                s3 += __builtin_amdgcn_exp2f(acc[4 * r + 3]);
            }
            esum += (s0 + s1) + (s2 + s3);
        }

        // combine m-halves (lanes l and l^32), accumulate weighted lse
        float tot = esum + __shfl_xor(esum, 32);
        racc = fmaf(sk2, __log2f(tot), racc);

        __syncthreads();   // abuf[1] free; abuf[0] (next expert) drained
    }

    // one atomic per row per family (lane halves hold identical tot-sums)
    if (half == 0)
        atomicAdd(&out[r0w + ln], racc);
}

extern "C" void kernel_launch(void* const* d_in, const int* in_sizes, int n_in,
                              void* d_out, int out_size, void* d_ws, size_t ws_size,
                              hipStream_t stream) {
    const float* x = (const float*)d_in[0];
    const float* s = (const float*)d_in[1];
    const float* a = (const float*)d_in[2];
    const float* b = (const float*)d_in[3];
    float* out = (float*)d_out;

    short* abff = (short*)d_ws;   // 16 experts x 20 KB = 320 KB

    prep_kernel<<<80, 256, 0, stream>>>(a, b, abff, out);
    fused_kernel<<<NROWS / 64, 256, 0, stream>>>(x, s, abff, out);
}